// Round 6
// baseline (809.501 us; speedup 1.0000x reference)
//
#include <hip/hip_runtime.h>
#include <hip/hip_bf16.h>
#include <math.h>

#define C_DIM 256
#define N_EMB 8192
#define N_Z   8192
#define HWB   1024
#define MBLK  128                 // z rows per filter block
#define NSPLIT 8                  // codebook splits (ns = bid&7 -> XCD-local)
#define SPLITC (N_EMB / NSPLIT)   // 1024 cols per split
#define NT    256                 // e cols per tile
#define NTILES (SPLITC / NT)      // 4
#define KC    64                  // k chunk (bf16)
#define CK    44                  // candidate slots per row
#define EPS   1.1e-3f             // >= 2*hard bound on |s_exact - s_approx| (~7.8e-4)
#define ZQ_ELEMS (N_Z * C_DIM)

typedef __attribute__((ext_vector_type(8))) short bf16x8;
typedef __attribute__((ext_vector_type(4))) float f32x4;
typedef unsigned short u16;
typedef unsigned int u32;

__device__ __forceinline__ float sqf(float x) { return __fmul_rn(x, x); }

__device__ __forceinline__ u16 f2bf(float v) {
  __hip_bfloat16 h = __float2bfloat16(v);
  u16 r; __builtin_memcpy(&r, &h, 2); return r;
}

// Exact replication of numpy pairwise summation of 256 squared elements.
template <int STRIDE>
__device__ float pw_sumsq_256(const float* __restrict__ a) {
  float h[2];
#pragma unroll
  for (int hh = 0; hh < 2; ++hh) {
    const float* p = a + hh * 128 * STRIDE;
    float r0 = sqf(p[0 * STRIDE]), r1 = sqf(p[1 * STRIDE]);
    float r2 = sqf(p[2 * STRIDE]), r3 = sqf(p[3 * STRIDE]);
    float r4 = sqf(p[4 * STRIDE]), r5 = sqf(p[5 * STRIDE]);
    float r6 = sqf(p[6 * STRIDE]), r7 = sqf(p[7 * STRIDE]);
    for (int i = 8; i < 128; i += 8) {
      r0 = __fadd_rn(r0, sqf(p[(i + 0) * STRIDE]));
      r1 = __fadd_rn(r1, sqf(p[(i + 1) * STRIDE]));
      r2 = __fadd_rn(r2, sqf(p[(i + 2) * STRIDE]));
      r3 = __fadd_rn(r3, sqf(p[(i + 3) * STRIDE]));
      r4 = __fadd_rn(r4, sqf(p[(i + 4) * STRIDE]));
      r5 = __fadd_rn(r5, sqf(p[(i + 5) * STRIDE]));
      r6 = __fadd_rn(r6, sqf(p[(i + 6) * STRIDE]));
      r7 = __fadd_rn(r7, sqf(p[(i + 7) * STRIDE]));
    }
    h[hh] = __fadd_rn(__fadd_rn(__fadd_rn(r0, r1), __fadd_rn(r2, r3)),
                      __fadd_rn(__fadd_rn(r4, r5), __fadd_rn(r6, r7)));
  }
  return __fadd_rn(h[0], h[1]);
}

// exact sequential dot (k = 0..255 ascending, xyzw) -- identical op order to
// the verified exact path of rounds 1-3.
__device__ __forceinline__ float exact_score(const float* __restrict__ zr,
                                             const float* __restrict__ er,
                                             float z2v, float e2v) {
  float d = 0.f;
  for (int k4 = 0; k4 < 64; ++k4) {
    float4 a4 = *(const float4*)(zr + k4 * 4);
    float4 b4 = *(const float4*)(er + k4 * 4);
    d = fmaf(a4.x, b4.x, d); d = fmaf(a4.y, b4.y, d);
    d = fmaf(a4.z, b4.z, d); d = fmaf(a4.w, b4.w, d);
  }
  return __fsub_rn(__fadd_rn(z2v, e2v), __fmul_rn(2.f, d));
}

// Transpose hid [b][c][hw] -> zt fp32 [n][c] and zbf bf16 [n][c].
__global__ void vq_tr(const float* __restrict__ hid, float* __restrict__ zt,
                      u16* __restrict__ zbf) {
  __shared__ float tl[32][33];
  int t = threadIdx.x;
  int tx = t & 31, ty = t >> 5;
  int bb = blockIdx.x >> 8;
  int r = blockIdx.x & 255;
  int cT = r >> 5, hwT = r & 31;
#pragma unroll
  for (int p = 0; p < 4; ++p)
    tl[ty + p * 8][tx] =
        hid[((size_t)bb * C_DIM + cT * 32 + ty + p * 8) * HWB + hwT * 32 + tx];
  __syncthreads();
#pragma unroll
  for (int p = 0; p < 4; ++p) {
    float v = tl[tx][ty + p * 8];
    size_t oi = ((size_t)bb * HWB + hwT * 32 + ty + p * 8) * C_DIM + cT * 32 + tx;
    zt[oi] = v;
    zbf[oi] = f2bf(v);
  }
}

// blocks 0..31: e2 + ebf; blocks 32..63: z2 (from zt)
__global__ void vq_norms(const float* __restrict__ zt, const float* __restrict__ emb,
                         float* __restrict__ z2, float* __restrict__ e2,
                         u16* __restrict__ ebf) {
  int t = threadIdx.x, b = blockIdx.x;
  if (b < 32) {
    int r = b * 256 + t;
    e2[r] = pw_sumsq_256<1>(emb + (size_t)r * C_DIM);
    for (int k4 = 0; k4 < 64; ++k4) {
      float4 v = *(const float4*)(emb + (size_t)r * C_DIM + k4 * 4);
      ushort4 o;
      o.x = f2bf(v.x); o.y = f2bf(v.y); o.z = f2bf(v.z); o.w = f2bf(v.w);
      *(ushort4*)(ebf + (size_t)r * C_DIM + k4 * 4) = o;
    }
  } else {
    int n = (b - 32) * 256 + t;
    z2[n] = pw_sumsq_256<1>(zt + (size_t)n * C_DIM);
  }
}

// MFMA bf16 filter + exact rescreen.
// Block: 512 thr = 8 waves as 2x4 over a 128-row x 256-col tile (wave: 64x64).
// acc[4][4] = 64 VGPR per thread -> no spill at the 128-reg cap (the round-5
// failure was acc[4][8]=128 VGPR spilling to scratch: WRITE_SIZE 54 MB).
// LDS tiles row-major 64 bf16/row (8 x 16B slots), slot ^= (row&7) swizzle.
// Approx s' tracks per-(wave,row) running min; cols within EPS go to per-row
// candidate lists; candidates re-scored EXACTLY, argmin lowest-index
// tie-break. Overflowed rows (statistically never) get a block-wide exact
// scan of the whole split -> correctness unconditional.
__global__ __launch_bounds__(512, 4) void vq_filter(
    const u16* __restrict__ zbf, const u16* __restrict__ ebf,
    const float* __restrict__ zt, const float* __restrict__ emb,
    const float* __restrict__ z2g, const float* __restrict__ e2g,
    float* __restrict__ cd, int* __restrict__ ci) {
  __shared__ u16 zl[MBLK * KC];       // 16 KB
  __shared__ u16 el[NT * KC];         // 32 KB
  __shared__ u16 rcol[MBLK * CK];     // 11 KB
  __shared__ int rcnt[MBLK];
  __shared__ int ovfr[16];
  __shared__ int novf;
  __shared__ float wbs[8];
  __shared__ int wis[8];

  int t = threadIdx.x;
  int mb = blockIdx.x >> 3;
  int ns = blockIdx.x & 7;
  int n0z = mb * MBLK;
  int l = t & 63;
  int w = t >> 6;
  int wr = w >> 2, wc = w & 3;     // 2 x 4 wave grid

  if (t < MBLK) rcnt[t] = 0;
  if (t == 0) novf = 0;

  float mp[4][4];
#pragma unroll
  for (int rf = 0; rf < 4; ++rf)
#pragma unroll
    for (int r = 0; r < 4; ++r) mp[rf][r] = INFINITY;

  const f32x4 vzero = {0.f, 0.f, 0.f, 0.f};

  for (int tile = 0; tile < NTILES; ++tile) {
    int ne0 = ns * SPLITC + tile * NT;
    f32x4 acc[4][4];
#pragma unroll
    for (int rf = 0; rf < 4; ++rf)
#pragma unroll
      for (int cf = 0; cf < 4; ++cf) acc[rf][cf] = vzero;

    for (int kc = 0; kc < C_DIM; kc += KC) {
      __syncthreads();
      // stage z chunk 128x64 (2 x uint4 per thread)
#pragma unroll
      for (int p = 0; p < 2; ++p) {
        int o = t + p * 512;
        int row = o >> 3, slot = o & 7;
        uint4 v = *(const uint4*)(zbf + (size_t)(n0z + row) * C_DIM + kc + slot * 8);
        *(uint4*)(zl + row * KC + ((slot ^ (row & 7)) << 3)) = v;
      }
      // stage e chunk 256x64 (4 x uint4 per thread)
#pragma unroll
      for (int p = 0; p < 4; ++p) {
        int o = t + p * 512;
        int row = o >> 3, slot = o & 7;
        uint4 v = *(const uint4*)(ebf + (size_t)(ne0 + row) * C_DIM + kc + slot * 8);
        *(uint4*)(el + row * KC + ((slot ^ (row & 7)) << 3)) = v;
      }
      __syncthreads();
#pragma unroll
      for (int ks = 0; ks < 2; ++ks) {
        int so = ((ks * 4 + (l >> 4)) ^ (l & 7)) << 3;
        bf16x8 a[4];
#pragma unroll
        for (int rf = 0; rf < 4; ++rf)
          a[rf] = *(const bf16x8*)(zl + (wr * 64 + rf * 16 + (l & 15)) * KC + so);
#pragma unroll
        for (int cf = 0; cf < 4; ++cf) {
          bf16x8 bfr = *(const bf16x8*)(el + (wc * 64 + cf * 16 + (l & 15)) * KC + so);
#pragma unroll
          for (int rf = 0; rf < 4; ++rf)
            acc[rf][cf] = __builtin_amdgcn_mfma_f32_16x16x32_bf16(a[rf], bfr, acc[rf][cf], 0, 0, 0);
        }
      }
    }
    // epilogue: approx scores, per-wave row minima, per-row candidate appends
    float e2s[4];
#pragma unroll
    for (int cf = 0; cf < 4; ++cf)
      e2s[cf] = e2g[ne0 + wc * 64 + cf * 16 + (l & 15)];
#pragma unroll
    for (int rf = 0; rf < 4; ++rf) {
#pragma unroll
      for (int r = 0; r < 4; ++r) {
        int rowl = wr * 64 + rf * 16 + (l >> 4) * 4 + r;
        float z2v = z2g[n0z + rowl];
        float mn = INFINITY;
#pragma unroll
        for (int cf = 0; cf < 4; ++cf) {
          float s = fmaf(-2.f, acc[rf][cf][r], z2v + e2s[cf]);
          mn = fminf(mn, s);
        }
#pragma unroll
        for (int m = 1; m < 16; m <<= 1)
          mn = fminf(mn, __shfl_xor(mn, m, 64));
        mp[rf][r] = fminf(mp[rf][r], mn);
        float thr = mp[rf][r] + EPS;
#pragma unroll
        for (int cf = 0; cf < 4; ++cf) {
          float s = fmaf(-2.f, acc[rf][cf][r], z2v + e2s[cf]);
          if (s <= thr) {
            int pos = atomicAdd(&rcnt[rowl], 1);
            if (pos < CK)
              rcol[rowl * CK + pos] = (u16)(ne0 + wc * 64 + cf * 16 + (l & 15));
          }
        }
      }
    }
  }
  __syncthreads();

  // exact rescreen: 4 threads per row, strided over that row's candidates
  {
    int row = t >> 2;
    int cnt = rcnt[row];
    float b = INFINITY; int bi = N_EMB;
    if (cnt <= CK) {
      const float* zr = zt + (size_t)(n0z + row) * C_DIM;
      float z2v = z2g[n0z + row];
      for (int p2 = (t & 3); p2 < cnt; p2 += 4) {
        int col = rcol[row * CK + p2];
        float s = exact_score(zr, emb + (size_t)col * C_DIM, z2v, e2g[col]);
        if (s < b || (s == b && col < bi)) { b = s; bi = col; }
      }
    }
#pragma unroll
    for (int m = 1; m <= 2; m <<= 1) {
      float ob = __shfl_xor(b, m, 64);
      int oi2 = __shfl_xor(bi, m, 64);
      if (ob < b || (ob == b && oi2 < bi)) { b = ob; bi = oi2; }
    }
    if ((t & 3) == 0 && cnt <= CK) {
      cd[ns * N_Z + n0z + row] = b;
      ci[ns * N_Z + n0z + row] = bi;
    }
  }

  // overflow fallback: exact scan of the full split for any overflowed row
  if (t < MBLK && rcnt[t] > CK) {
    int p = atomicAdd(&novf, 1);
    if (p < 16) ovfr[p] = t;
  }
  __syncthreads();
  int no = min(novf, 16);
  for (int oi = 0; oi < no; ++oi) {
    int row = ovfr[oi];
    const float* zr = zt + (size_t)(n0z + row) * C_DIM;
    float z2v = z2g[n0z + row];
    float b = INFINITY; int bi = N_EMB;
#pragma unroll
    for (int q = 0; q < 2; ++q) {
      int col = ns * SPLITC + t * 2 + q;
      float s = exact_score(zr, emb + (size_t)col * C_DIM, z2v, e2g[col]);
      if (s < b || (s == b && col < bi)) { b = s; bi = col; }
    }
#pragma unroll
    for (int m = 1; m <= 32; m <<= 1) {
      float ob = __shfl_xor(b, m, 64);
      int oi2 = __shfl_xor(bi, m, 64);
      if (ob < b || (ob == b && oi2 < bi)) { b = ob; bi = oi2; }
    }
    if (l == 0) { wbs[w] = b; wis[w] = bi; }
    __syncthreads();
    if (t == 0) {
      for (int w2 = 1; w2 < 8; ++w2)
        if (wbs[w2] < b || (wbs[w2] == b && wis[w2] < bi)) { b = wbs[w2]; bi = wis[w2]; }
      cd[ns * N_Z + n0z + row] = b;
      ci[ns * N_Z + n0z + row] = bi;
    }
    __syncthreads();
  }
}

// merge NSPLIT candidates per row, write indices (as float) and gather z_q
__global__ void vq_out(const float* __restrict__ emb, const float* __restrict__ cd,
                       const int* __restrict__ ci, float* __restrict__ out) {
  __shared__ int sidx[32];
  int t = threadIdx.x;
  int n0 = blockIdx.x * 32;
  if (t < 32) {
    int n = n0 + t;
    float b = INFINITY;
    int bi = 0;
    for (int ns = 0; ns < NSPLIT; ++ns) {        // ascending split = ascending idx
      float d = cd[ns * N_Z + n];
      int i = ci[ns * N_Z + n];
      if (d < b || (d == b && i < bi)) { b = d; bi = i; }
    }
    sidx[t] = bi;
    out[ZQ_ELEMS + n] = (float)bi;
  }
  __syncthreads();
  int bb = n0 >> 10, hw0 = n0 & 1023;
  int nl = t & 31, cg = t >> 5;
#pragma unroll
  for (int p = 0; p < 8; ++p) {
    int c0 = cg * 4 + p * 32;
    float4 v = *(const float4*)(emb + (size_t)sidx[nl] * C_DIM + c0);
    out[((size_t)bb * C_DIM + c0 + 0) * HWB + hw0 + nl] = v.x;
    out[((size_t)bb * C_DIM + c0 + 1) * HWB + hw0 + nl] = v.y;
    out[((size_t)bb * C_DIM + c0 + 2) * HWB + hw0 + nl] = v.z;
    out[((size_t)bb * C_DIM + c0 + 3) * HWB + hw0 + nl] = v.w;
  }
}

extern "C" void kernel_launch(void* const* d_in, const int* in_sizes, int n_in,
                              void* d_out, int out_size, void* d_ws, size_t ws_size,
                              hipStream_t stream) {
  const float* hid = (const float*)d_in[0];
  const float* emb = (const float*)d_in[1];
  float* out = (float*)d_out;

  float* zt = (float*)d_ws;                        // 8 MB
  float* z2 = zt + (size_t)N_Z * C_DIM;            // 8192
  float* e2 = z2 + N_Z;                            // 8192
  float* cd = e2 + N_EMB;                          // 65536
  int* ci = (int*)(cd + (size_t)NSPLIT * N_Z);     // 65536
  u16* zbf = (u16*)(ci + (size_t)NSPLIT * N_Z);    // 4 MB
  u16* ebf = zbf + (size_t)N_Z * C_DIM;            // 4 MB

  vq_tr<<<2048, 256, 0, stream>>>(hid, zt, zbf);
  vq_norms<<<64, 256, 0, stream>>>(zt, emb, z2, e2, ebf);
  vq_filter<<<(N_Z / MBLK) * NSPLIT, 512, 0, stream>>>(zbf, ebf, zt, emb, z2, e2, cd, ci);
  vq_out<<<N_Z / 32, 256, 0, stream>>>(emb, cd, ci, out);
}

// Round 7
// 447.100 us; speedup vs baseline: 1.8106x; 1.8106x over previous
//
#include <hip/hip_runtime.h>
#include <hip/hip_bf16.h>
#include <math.h>

#define C_DIM 256
#define N_EMB 8192
#define N_Z   8192
#define HWB   1024
#define MBLK  128                 // z rows per filter block
#define NSPLIT 8                  // codebook splits (ns = bid&7 -> XCD-local)
#define SPLITC (N_EMB / NSPLIT)   // 1024 cols per split
#define NT    128                 // e cols per tile
#define NTILES (SPLITC / NT)      // 8
#define KC    64                  // k chunk (bf16)
#define CK    44                  // candidate slots per row
#define EPS   1.1e-3f             // >= 2*hard bound on |s_exact - s_approx| (~7.8e-4)
#define ZQ_ELEMS (N_Z * C_DIM)

typedef __attribute__((ext_vector_type(8))) short bf16x8;
typedef __attribute__((ext_vector_type(4))) float f32x4;
typedef unsigned short u16;
typedef unsigned int u32;

__device__ __forceinline__ float sqf(float x) { return __fmul_rn(x, x); }

__device__ __forceinline__ u16 f2bf(float v) {
  __hip_bfloat16 h = __float2bfloat16(v);
  u16 r; __builtin_memcpy(&r, &h, 2); return r;
}

// Exact replication of numpy pairwise summation of 256 squared elements.
template <int STRIDE>
__device__ float pw_sumsq_256(const float* __restrict__ a) {
  float h[2];
#pragma unroll
  for (int hh = 0; hh < 2; ++hh) {
    const float* p = a + hh * 128 * STRIDE;
    float r0 = sqf(p[0 * STRIDE]), r1 = sqf(p[1 * STRIDE]);
    float r2 = sqf(p[2 * STRIDE]), r3 = sqf(p[3 * STRIDE]);
    float r4 = sqf(p[4 * STRIDE]), r5 = sqf(p[5 * STRIDE]);
    float r6 = sqf(p[6 * STRIDE]), r7 = sqf(p[7 * STRIDE]);
    for (int i = 8; i < 128; i += 8) {
      r0 = __fadd_rn(r0, sqf(p[(i + 0) * STRIDE]));
      r1 = __fadd_rn(r1, sqf(p[(i + 1) * STRIDE]));
      r2 = __fadd_rn(r2, sqf(p[(i + 2) * STRIDE]));
      r3 = __fadd_rn(r3, sqf(p[(i + 3) * STRIDE]));
      r4 = __fadd_rn(r4, sqf(p[(i + 4) * STRIDE]));
      r5 = __fadd_rn(r5, sqf(p[(i + 5) * STRIDE]));
      r6 = __fadd_rn(r6, sqf(p[(i + 6) * STRIDE]));
      r7 = __fadd_rn(r7, sqf(p[(i + 7) * STRIDE]));
    }
    h[hh] = __fadd_rn(__fadd_rn(__fadd_rn(r0, r1), __fadd_rn(r2, r3)),
                      __fadd_rn(__fadd_rn(r4, r5), __fadd_rn(r6, r7)));
  }
  return __fadd_rn(h[0], h[1]);
}

// exact sequential dot (k = 0..255 ascending, xyzw) -- identical op order to
// the verified exact path of rounds 1-3.
__device__ __forceinline__ float exact_score(const float* __restrict__ zr,
                                             const float* __restrict__ er,
                                             float z2v, float e2v) {
  float d = 0.f;
  for (int k4 = 0; k4 < 64; ++k4) {
    float4 a4 = *(const float4*)(zr + k4 * 4);
    float4 b4 = *(const float4*)(er + k4 * 4);
    d = fmaf(a4.x, b4.x, d); d = fmaf(a4.y, b4.y, d);
    d = fmaf(a4.z, b4.z, d); d = fmaf(a4.w, b4.w, d);
  }
  return __fsub_rn(__fadd_rn(z2v, e2v), __fmul_rn(2.f, d));
}

// Transpose hid [b][c][hw] -> zt fp32 [n][c] and zbf bf16 [n][c].
__global__ void vq_tr(const float* __restrict__ hid, float* __restrict__ zt,
                      u16* __restrict__ zbf) {
  __shared__ float tl[32][33];
  int t = threadIdx.x;
  int tx = t & 31, ty = t >> 5;
  int bb = blockIdx.x >> 8;
  int r = blockIdx.x & 255;
  int cT = r >> 5, hwT = r & 31;
#pragma unroll
  for (int p = 0; p < 4; ++p)
    tl[ty + p * 8][tx] =
        hid[((size_t)bb * C_DIM + cT * 32 + ty + p * 8) * HWB + hwT * 32 + tx];
  __syncthreads();
#pragma unroll
  for (int p = 0; p < 4; ++p) {
    float v = tl[tx][ty + p * 8];
    size_t oi = ((size_t)bb * HWB + hwT * 32 + ty + p * 8) * C_DIM + cT * 32 + tx;
    zt[oi] = v;
    zbf[oi] = f2bf(v);
  }
}

// blocks 0..31: e2 + ebf; blocks 32..63: z2 (from zt)
__global__ void vq_norms(const float* __restrict__ zt, const float* __restrict__ emb,
                         float* __restrict__ z2, float* __restrict__ e2,
                         u16* __restrict__ ebf) {
  int t = threadIdx.x, b = blockIdx.x;
  if (b < 32) {
    int r = b * 256 + t;
    e2[r] = pw_sumsq_256<1>(emb + (size_t)r * C_DIM);
    for (int k4 = 0; k4 < 64; ++k4) {
      float4 v = *(const float4*)(emb + (size_t)r * C_DIM + k4 * 4);
      ushort4 o;
      o.x = f2bf(v.x); o.y = f2bf(v.y); o.z = f2bf(v.z); o.w = f2bf(v.w);
      *(ushort4*)(ebf + (size_t)r * C_DIM + k4 * 4) = o;
    }
  } else {
    int n = (b - 32) * 256 + t;
    z2[n] = pw_sumsq_256<1>(zt + (size_t)n * C_DIM);
  }
}

// MFMA bf16 filter + exact rescreen.
// Block: 512 thr = 8 waves as 4x2 over a 128-row x 128-col tile.
// Wave tile 32x64 -> acc[2][4] = 32 regs/thread; NO launch-bounds occupancy
// pin (rounds 5/6 both died to cap-forced scratch spill: WRITE_SIZE 54/161 MB).
// LDS tiles row-major 64 bf16/row (8 x 16B slots), slot ^= (row&7) swizzle.
// Approx s' tracks per-(wave,row) running min; cols within EPS go to per-row
// candidate lists; candidates re-scored EXACTLY, argmin lowest-index
// tie-break. Overflowed rows (statistically never) get a block-wide exact
// scan of the whole split -> correctness unconditional.
__global__ __launch_bounds__(512) void vq_filter(
    const u16* __restrict__ zbf, const u16* __restrict__ ebf,
    const float* __restrict__ zt, const float* __restrict__ emb,
    const float* __restrict__ z2g, const float* __restrict__ e2g,
    float* __restrict__ cd, int* __restrict__ ci) {
  __shared__ u16 zl[MBLK * KC];       // 16 KB
  __shared__ u16 el[NT * KC];         // 16 KB
  __shared__ u16 rcol[MBLK * CK];     // 11 KB
  __shared__ int rcnt[MBLK];
  __shared__ int ovfr[16];
  __shared__ int novf;
  __shared__ float wbs[8];
  __shared__ int wis[8];

  int t = threadIdx.x;
  int mb = blockIdx.x >> 3;
  int ns = blockIdx.x & 7;
  int n0z = mb * MBLK;
  int l = t & 63;
  int w = t >> 6;
  int wr = w >> 1, wc = w & 1;     // 4 x 2 wave grid

  if (t < MBLK) rcnt[t] = 0;
  if (t == 0) novf = 0;

  // z2 per (rf,r) is tile-invariant: hoist (8 regs)
  float z2r[2][4];
#pragma unroll
  for (int rf = 0; rf < 2; ++rf)
#pragma unroll
    for (int r = 0; r < 4; ++r)
      z2r[rf][r] = z2g[n0z + wr * 32 + rf * 16 + (l >> 4) * 4 + r];

  float mp[2][4];
#pragma unroll
  for (int rf = 0; rf < 2; ++rf)
#pragma unroll
    for (int r = 0; r < 4; ++r) mp[rf][r] = INFINITY;

  const f32x4 vzero = {0.f, 0.f, 0.f, 0.f};

  for (int tile = 0; tile < NTILES; ++tile) {
    int ne0 = ns * SPLITC + tile * NT;
    f32x4 acc[2][4];
#pragma unroll
    for (int rf = 0; rf < 2; ++rf)
#pragma unroll
      for (int cf = 0; cf < 4; ++cf) acc[rf][cf] = vzero;

    for (int kc = 0; kc < C_DIM; kc += KC) {
      __syncthreads();
      // stage z chunk 128x64 (2 x uint4 per thread)
#pragma unroll
      for (int p = 0; p < 2; ++p) {
        int o = t + p * 512;
        int row = o >> 3, slot = o & 7;
        uint4 v = *(const uint4*)(zbf + (size_t)(n0z + row) * C_DIM + kc + slot * 8);
        *(uint4*)(zl + row * KC + ((slot ^ (row & 7)) << 3)) = v;
      }
      // stage e chunk 128x64 (2 x uint4 per thread)
#pragma unroll
      for (int p = 0; p < 2; ++p) {
        int o = t + p * 512;
        int row = o >> 3, slot = o & 7;
        uint4 v = *(const uint4*)(ebf + (size_t)(ne0 + row) * C_DIM + kc + slot * 8);
        *(uint4*)(el + row * KC + ((slot ^ (row & 7)) << 3)) = v;
      }
      __syncthreads();
#pragma unroll
      for (int ks = 0; ks < 2; ++ks) {
        int so = ((ks * 4 + (l >> 4)) ^ (l & 7)) << 3;
        bf16x8 a[2];
#pragma unroll
        for (int rf = 0; rf < 2; ++rf)
          a[rf] = *(const bf16x8*)(zl + (wr * 32 + rf * 16 + (l & 15)) * KC + so);
#pragma unroll
        for (int cf = 0; cf < 4; ++cf) {
          bf16x8 bfr = *(const bf16x8*)(el + (wc * 64 + cf * 16 + (l & 15)) * KC + so);
#pragma unroll
          for (int rf = 0; rf < 2; ++rf)
            acc[rf][cf] = __builtin_amdgcn_mfma_f32_16x16x32_bf16(a[rf], bfr, acc[rf][cf], 0, 0, 0);
        }
      }
    }
    // epilogue: approx scores, per-wave row minima, per-row candidate appends
    float e2s[4];
#pragma unroll
    for (int cf = 0; cf < 4; ++cf)
      e2s[cf] = e2g[ne0 + wc * 64 + cf * 16 + (l & 15)];
#pragma unroll
    for (int rf = 0; rf < 2; ++rf) {
#pragma unroll
      for (int r = 0; r < 4; ++r) {
        int rowl = wr * 32 + rf * 16 + (l >> 4) * 4 + r;
        float z2v = z2r[rf][r];
        float mn = INFINITY;
#pragma unroll
        for (int cf = 0; cf < 4; ++cf) {
          float s = fmaf(-2.f, acc[rf][cf][r], z2v + e2s[cf]);
          mn = fminf(mn, s);
        }
#pragma unroll
        for (int m = 1; m < 16; m <<= 1)
          mn = fminf(mn, __shfl_xor(mn, m, 64));
        mp[rf][r] = fminf(mp[rf][r], mn);
        float thr = mp[rf][r] + EPS;
#pragma unroll
        for (int cf = 0; cf < 4; ++cf) {
          float s = fmaf(-2.f, acc[rf][cf][r], z2v + e2s[cf]);
          if (s <= thr) {
            int pos = atomicAdd(&rcnt[rowl], 1);
            if (pos < CK)
              rcol[rowl * CK + pos] = (u16)(ne0 + wc * 64 + cf * 16 + (l & 15));
          }
        }
      }
    }
  }
  __syncthreads();

  // exact rescreen: 4 threads per row, strided over that row's candidates
  {
    int row = t >> 2;
    int cnt = rcnt[row];
    float b = INFINITY; int bi = N_EMB;
    if (cnt <= CK) {
      const float* zr = zt + (size_t)(n0z + row) * C_DIM;
      float z2v = z2g[n0z + row];
      for (int p2 = (t & 3); p2 < cnt; p2 += 4) {
        int col = rcol[row * CK + p2];
        float s = exact_score(zr, emb + (size_t)col * C_DIM, z2v, e2g[col]);
        if (s < b || (s == b && col < bi)) { b = s; bi = col; }
      }
    }
#pragma unroll
    for (int m = 1; m <= 2; m <<= 1) {
      float ob = __shfl_xor(b, m, 64);
      int oi2 = __shfl_xor(bi, m, 64);
      if (ob < b || (ob == b && oi2 < bi)) { b = ob; bi = oi2; }
    }
    if ((t & 3) == 0 && cnt <= CK) {
      cd[ns * N_Z + n0z + row] = b;
      ci[ns * N_Z + n0z + row] = bi;
    }
  }

  // overflow fallback: exact scan of the full split for any overflowed row
  if (t < MBLK && rcnt[t] > CK) {
    int p = atomicAdd(&novf, 1);
    if (p < 16) ovfr[p] = t;
  }
  __syncthreads();
  int no = min(novf, 16);
  for (int oi = 0; oi < no; ++oi) {
    int row = ovfr[oi];
    const float* zr = zt + (size_t)(n0z + row) * C_DIM;
    float z2v = z2g[n0z + row];
    float b = INFINITY; int bi = N_EMB;
#pragma unroll
    for (int q = 0; q < 2; ++q) {
      int col = ns * SPLITC + t * 2 + q;
      float s = exact_score(zr, emb + (size_t)col * C_DIM, z2v, e2g[col]);
      if (s < b || (s == b && col < bi)) { b = s; bi = col; }
    }
#pragma unroll
    for (int m = 1; m <= 32; m <<= 1) {
      float ob = __shfl_xor(b, m, 64);
      int oi2 = __shfl_xor(bi, m, 64);
      if (ob < b || (ob == b && oi2 < bi)) { b = ob; bi = oi2; }
    }
    if (l == 0) { wbs[w] = b; wis[w] = bi; }
    __syncthreads();
    if (t == 0) {
      for (int w2 = 1; w2 < 8; ++w2)
        if (wbs[w2] < b || (wbs[w2] == b && wis[w2] < bi)) { b = wbs[w2]; bi = wis[w2]; }
      cd[ns * N_Z + n0z + row] = b;
      ci[ns * N_Z + n0z + row] = bi;
    }
    __syncthreads();
  }
}

// merge NSPLIT candidates per row, write indices (as float) and gather z_q
__global__ void vq_out(const float* __restrict__ emb, const float* __restrict__ cd,
                       const int* __restrict__ ci, float* __restrict__ out) {
  __shared__ int sidx[32];
  int t = threadIdx.x;
  int n0 = blockIdx.x * 32;
  if (t < 32) {
    int n = n0 + t;
    float b = INFINITY;
    int bi = 0;
    for (int ns = 0; ns < NSPLIT; ++ns) {        // ascending split = ascending idx
      float d = cd[ns * N_Z + n];
      int i = ci[ns * N_Z + n];
      if (d < b || (d == b && i < bi)) { b = d; bi = i; }
    }
    sidx[t] = bi;
    out[ZQ_ELEMS + n] = (float)bi;
  }
  __syncthreads();
  int bb = n0 >> 10, hw0 = n0 & 1023;
  int nl = t & 31, cg = t >> 5;
#pragma unroll
  for (int p = 0; p < 8; ++p) {
    int c0 = cg * 4 + p * 32;
    float4 v = *(const float4*)(emb + (size_t)sidx[nl] * C_DIM + c0);
    out[((size_t)bb * C_DIM + c0 + 0) * HWB + hw0 + nl] = v.x;
    out[((size_t)bb * C_DIM + c0 + 1) * HWB + hw0 + nl] = v.y;
    out[((size_t)bb * C_DIM + c0 + 2) * HWB + hw0 + nl] = v.z;
    out[((size_t)bb * C_DIM + c0 + 3) * HWB + hw0 + nl] = v.w;
  }
}

extern "C" void kernel_launch(void* const* d_in, const int* in_sizes, int n_in,
                              void* d_out, int out_size, void* d_ws, size_t ws_size,
                              hipStream_t stream) {
  const float* hid = (const float*)d_in[0];
  const float* emb = (const float*)d_in[1];
  float* out = (float*)d_out;

  float* zt = (float*)d_ws;                        // 8 MB
  float* z2 = zt + (size_t)N_Z * C_DIM;            // 8192
  float* e2 = z2 + N_Z;                            // 8192
  float* cd = e2 + N_EMB;                          // 65536
  int* ci = (int*)(cd + (size_t)NSPLIT * N_Z);     // 65536
  u16* zbf = (u16*)(ci + (size_t)NSPLIT * N_Z);    // 4 MB
  u16* ebf = zbf + (size_t)N_Z * C_DIM;            // 4 MB

  vq_tr<<<2048, 256, 0, stream>>>(hid, zt, zbf);
  vq_norms<<<64, 256, 0, stream>>>(zt, emb, z2, e2, ebf);
  vq_filter<<<(N_Z / MBLK) * NSPLIT, 512, 0, stream>>>(zbf, ebf, zt, emb, z2, e2, cd, ci);
  vq_out<<<N_Z / 32, 256, 0, stream>>>(emb, cd, ci, out);
}

// Round 8
// 231.251 us; speedup vs baseline: 3.5005x; 1.9334x over previous
//
#include <hip/hip_runtime.h>
#include <hip/hip_bf16.h>
#include <math.h>

#define C_DIM 256
#define N_EMB 8192
#define N_Z   8192
#define HWB   1024
#define MBLK  128                 // z rows per filter block
#define NSPLIT 8                  // codebook splits (ns = bid&7 -> XCD-local)
#define SPLITC (N_EMB / NSPLIT)   // 1024 cols per split
#define NT    128                 // e cols per tile
#define NTILES (SPLITC / NT)      // 8
#define KC    64                  // k chunk (bf16)
#define NSTEPS (NTILES * 4)       // 32 stage-steps per pass
#define CK    32                  // candidate slots per row
#define EPS   1.1e-3f             // >= 2*hard bound on |s_exact - s_approx| (~7.8e-4)
#define ZQ_ELEMS (N_Z * C_DIM)

typedef __attribute__((ext_vector_type(8))) short bf16x8;
typedef __attribute__((ext_vector_type(4))) float f32x4;
typedef unsigned short u16;
typedef unsigned int u32;

__device__ __forceinline__ float sqf(float x) { return __fmul_rn(x, x); }

__device__ __forceinline__ u16 f2bf(float v) {
  __hip_bfloat16 h = __float2bfloat16(v);
  u16 r; __builtin_memcpy(&r, &h, 2); return r;
}

// Exact replication of numpy pairwise summation of 256 squared elements.
template <int STRIDE>
__device__ float pw_sumsq_256(const float* __restrict__ a) {
  float h[2];
#pragma unroll
  for (int hh = 0; hh < 2; ++hh) {
    const float* p = a + hh * 128 * STRIDE;
    float r0 = sqf(p[0 * STRIDE]), r1 = sqf(p[1 * STRIDE]);
    float r2 = sqf(p[2 * STRIDE]), r3 = sqf(p[3 * STRIDE]);
    float r4 = sqf(p[4 * STRIDE]), r5 = sqf(p[5 * STRIDE]);
    float r6 = sqf(p[6 * STRIDE]), r7 = sqf(p[7 * STRIDE]);
    for (int i = 8; i < 128; i += 8) {
      r0 = __fadd_rn(r0, sqf(p[(i + 0) * STRIDE]));
      r1 = __fadd_rn(r1, sqf(p[(i + 1) * STRIDE]));
      r2 = __fadd_rn(r2, sqf(p[(i + 2) * STRIDE]));
      r3 = __fadd_rn(r3, sqf(p[(i + 3) * STRIDE]));
      r4 = __fadd_rn(r4, sqf(p[(i + 4) * STRIDE]));
      r5 = __fadd_rn(r5, sqf(p[(i + 5) * STRIDE]));
      r6 = __fadd_rn(r6, sqf(p[(i + 6) * STRIDE]));
      r7 = __fadd_rn(r7, sqf(p[(i + 7) * STRIDE]));
    }
    h[hh] = __fadd_rn(__fadd_rn(__fadd_rn(r0, r1), __fadd_rn(r2, r3)),
                      __fadd_rn(__fadd_rn(r4, r5), __fadd_rn(r6, r7)));
  }
  return __fadd_rn(h[0], h[1]);
}

// exact sequential dot (k = 0..255 ascending, xyzw) -- identical op order to
// the verified exact path of rounds 1-3.
__device__ __forceinline__ float exact_score(const float* __restrict__ zr,
                                             const float* __restrict__ er,
                                             float z2v, float e2v) {
  float d = 0.f;
  for (int k4 = 0; k4 < 64; ++k4) {
    float4 a4 = *(const float4*)(zr + k4 * 4);
    float4 b4 = *(const float4*)(er + k4 * 4);
    d = fmaf(a4.x, b4.x, d); d = fmaf(a4.y, b4.y, d);
    d = fmaf(a4.z, b4.z, d); d = fmaf(a4.w, b4.w, d);
  }
  return __fsub_rn(__fadd_rn(z2v, e2v), __fmul_rn(2.f, d));
}

// Transpose hid [b][c][hw] -> zt fp32 [n][c] and zbf bf16 [n][c].
__global__ void vq_tr(const float* __restrict__ hid, float* __restrict__ zt,
                      u16* __restrict__ zbf) {
  __shared__ float tl[32][33];
  int t = threadIdx.x;
  int tx = t & 31, ty = t >> 5;
  int bb = blockIdx.x >> 8;
  int r = blockIdx.x & 255;
  int cT = r >> 5, hwT = r & 31;
#pragma unroll
  for (int p = 0; p < 4; ++p)
    tl[ty + p * 8][tx] =
        hid[((size_t)bb * C_DIM + cT * 32 + ty + p * 8) * HWB + hwT * 32 + tx];
  __syncthreads();
#pragma unroll
  for (int p = 0; p < 4; ++p) {
    float v = tl[tx][ty + p * 8];
    size_t oi = ((size_t)bb * HWB + hwT * 32 + ty + p * 8) * C_DIM + cT * 32 + tx;
    zt[oi] = v;
    zbf[oi] = f2bf(v);
  }
}

// blocks 0..31: e2 + ebf; blocks 32..63: z2 (from zt)
__global__ void vq_norms(const float* __restrict__ zt, const float* __restrict__ emb,
                         float* __restrict__ z2, float* __restrict__ e2,
                         u16* __restrict__ ebf) {
  int t = threadIdx.x, b = blockIdx.x;
  if (b < 32) {
    int r = b * 256 + t;
    e2[r] = pw_sumsq_256<1>(emb + (size_t)r * C_DIM);
    for (int k4 = 0; k4 < 64; ++k4) {
      float4 v = *(const float4*)(emb + (size_t)r * C_DIM + k4 * 4);
      ushort4 o;
      o.x = f2bf(v.x); o.y = f2bf(v.y); o.z = f2bf(v.z); o.w = f2bf(v.w);
      *(ushort4*)(ebf + (size_t)r * C_DIM + k4 * 4) = o;
    }
  } else {
    int n = (b - 32) * 256 + t;
    z2[n] = pw_sumsq_256<1>(zt + (size_t)n * C_DIM);
  }
}

// Two-pass MFMA filter + exact rescreen.
// Pass A: MFMA-only loop, per-lane running min (no shfl/atomics in hot loop);
//         one final cross-lane reduce + LDS atomicMin (float-bits, s>0).
// Pass B: recompute MFMA (bit-identical) and append cols with s' <= m_row+EPS
//         (tight final threshold -> ~1-3 appends/row, winner guaranteed).
// Staging is register-prefetched (T14): next step's 4 x uint4 loaded during
// current MFMA; barriers only cover the LDS writes.
// Candidates re-scored EXACTLY (sequential fmaf, numpy expr), lowest-index
// tie-break. Overflowed rows (statistically never) -> exact full-split scan.
__global__ __launch_bounds__(512) void vq_filter(
    const u16* __restrict__ zbf, const u16* __restrict__ ebf,
    const float* __restrict__ zt, const float* __restrict__ emb,
    const float* __restrict__ z2g, const float* __restrict__ e2g,
    float* __restrict__ cd, int* __restrict__ ci) {
  __shared__ u16 zl[MBLK * KC];       // 16 KB
  __shared__ u16 el[NT * KC];         // 16 KB
  __shared__ float e2l[SPLITC];       // 4 KB
  __shared__ u32 mrow[MBLK];          // 512 B (float bits of row min)
  __shared__ u16 rcol[MBLK * CK];     // 8 KB
  __shared__ int rcnt[MBLK];
  __shared__ int ovfr[16];
  __shared__ int novf;
  __shared__ float wbs[8];
  __shared__ int wis[8];

  int t = threadIdx.x;
  int mb = blockIdx.x >> 3;
  int ns = blockIdx.x & 7;
  int n0z = mb * MBLK;
  int l = t & 63;
  int w = t >> 6;
  int wr = w >> 1, wc = w & 1;     // 4 x 2 wave grid, wave tile 32 x 64

  if (t < MBLK) { rcnt[t] = 0; mrow[t] = 0x7f800000u; }
  if (t == 0) novf = 0;
  for (int i = t; i < SPLITC; i += 512) e2l[i] = e2g[ns * SPLITC + i];

  // hoisted z2 per (rf,r)
  float z2r[2][4];
#pragma unroll
  for (int rf = 0; rf < 2; ++rf)
#pragma unroll
    for (int r = 0; r < 4; ++r)
      z2r[rf][r] = z2g[n0z + wr * 32 + rf * 16 + (l >> 4) * 4 + r];

  float mpl[2][4];
#pragma unroll
  for (int rf = 0; rf < 2; ++rf)
#pragma unroll
    for (int r = 0; r < 4; ++r) mpl[rf][r] = INFINITY;

  const f32x4 vzero = {0.f, 0.f, 0.f, 0.f};
  const int o0r = t >> 3, o0s = t & 7;            // staging lane->(row,slot)
  const int o1r = (t + 512) >> 3, o1s = t & 7;    // second element
  const int w0off = o0r * KC + ((o0s ^ (o0r & 7)) << 3);
  const int w1off = o1r * KC + ((o1s ^ (o1r & 7)) << 3);

  uint4 gz0, gz1, ge0, ge1;
  // prologue: prefetch step 0
  {
    const u16* bz = zbf + (size_t)n0z * C_DIM;
    const u16* be = ebf + (size_t)(ns * SPLITC) * C_DIM;
    gz0 = *(const uint4*)(bz + (size_t)o0r * C_DIM + o0s * 8);
    gz1 = *(const uint4*)(bz + (size_t)o1r * C_DIM + o1s * 8);
    ge0 = *(const uint4*)(be + (size_t)o0r * C_DIM + o0s * 8);
    ge1 = *(const uint4*)(be + (size_t)o1r * C_DIM + o1s * 8);
  }

#pragma unroll 1
  for (int pass = 0; pass < 2; ++pass) {
#pragma unroll 1
    for (int tile = 0; tile < NTILES; ++tile) {
      f32x4 acc[2][4];
#pragma unroll
      for (int rf = 0; rf < 2; ++rf)
#pragma unroll
        for (int cf = 0; cf < 4; ++cf) acc[rf][cf] = vzero;

#pragma unroll 1
      for (int kcs = 0; kcs < 4; ++kcs) {
        int stG = pass * NSTEPS + tile * 4 + kcs;
        __syncthreads();               // prior MFMA done reading LDS
        *(uint4*)(zl + w0off) = gz0;
        *(uint4*)(zl + w1off) = gz1;
        *(uint4*)(el + w0off) = ge0;
        *(uint4*)(el + w1off) = ge1;
        if (stG + 1 < 2 * NSTEPS) {    // prefetch next step
          int ps = (stG + 1) & (NSTEPS - 1);
          int kc = (ps & 3) * KC;
          int ne0 = ns * SPLITC + (ps >> 2) * NT;
          const u16* bz = zbf + (size_t)n0z * C_DIM + kc;
          const u16* be = ebf + (size_t)ne0 * C_DIM + kc;
          gz0 = *(const uint4*)(bz + (size_t)o0r * C_DIM + o0s * 8);
          gz1 = *(const uint4*)(bz + (size_t)o1r * C_DIM + o1s * 8);
          ge0 = *(const uint4*)(be + (size_t)o0r * C_DIM + o0s * 8);
          ge1 = *(const uint4*)(be + (size_t)o1r * C_DIM + o1s * 8);
        }
        __syncthreads();               // LDS ready
#pragma unroll
        for (int ks = 0; ks < 2; ++ks) {
          int so = ((ks * 4 + (l >> 4)) ^ (l & 7)) << 3;
          bf16x8 a0 = *(const bf16x8*)(zl + (wr * 32 + (l & 15)) * KC + so);
          bf16x8 a1 = *(const bf16x8*)(zl + (wr * 32 + 16 + (l & 15)) * KC + so);
#pragma unroll
          for (int cf = 0; cf < 4; ++cf) {
            bf16x8 bfr = *(const bf16x8*)(el + (wc * 64 + cf * 16 + (l & 15)) * KC + so);
            acc[0][cf] = __builtin_amdgcn_mfma_f32_16x16x32_bf16(a0, bfr, acc[0][cf], 0, 0, 0);
            acc[1][cf] = __builtin_amdgcn_mfma_f32_16x16x32_bf16(a1, bfr, acc[1][cf], 0, 0, 0);
          }
        }
      }
      // per-tile epilogue (no cross-lane ops in pass A)
      float e2s[4];
#pragma unroll
      for (int cf = 0; cf < 4; ++cf)
        e2s[cf] = e2l[tile * NT + wc * 64 + cf * 16 + (l & 15)];
      if (pass == 0) {
#pragma unroll
        for (int rf = 0; rf < 2; ++rf)
#pragma unroll
          for (int r = 0; r < 4; ++r) {
            float z2v = z2r[rf][r];
            float mn = mpl[rf][r];
#pragma unroll
            for (int cf = 0; cf < 4; ++cf)
              mn = fminf(mn, fmaf(-2.f, acc[rf][cf][r], z2v + e2s[cf]));
            mpl[rf][r] = mn;
          }
      } else {
        int ne0 = ns * SPLITC + tile * NT;
#pragma unroll
        for (int rf = 0; rf < 2; ++rf)
#pragma unroll
          for (int r = 0; r < 4; ++r) {
            int rowl = wr * 32 + rf * 16 + (l >> 4) * 4 + r;
            float z2v = z2r[rf][r];
            float thr = mpl[rf][r];
#pragma unroll
            for (int cf = 0; cf < 4; ++cf) {
              float s = fmaf(-2.f, acc[rf][cf][r], z2v + e2s[cf]);
              if (s <= thr) {
                int pos = atomicAdd(&rcnt[rowl], 1);
                if (pos < CK)
                  rcol[rowl * CK + pos] = (u16)(ne0 + wc * 64 + cf * 16 + (l & 15));
              }
            }
          }
      }
    }
    if (pass == 0) {
      // single cross-lane reduce + atomicMin (float bits; all s > 0)
#pragma unroll
      for (int rf = 0; rf < 2; ++rf)
#pragma unroll
        for (int r = 0; r < 4; ++r) {
          float mn = mpl[rf][r];
#pragma unroll
          for (int m = 1; m < 16; m <<= 1)
            mn = fminf(mn, __shfl_xor(mn, m, 64));
          if ((l & 15) == 0) {
            int rowl = wr * 32 + rf * 16 + (l >> 4) * 4 + r;
            atomicMin(&mrow[rowl], __float_as_uint(mn));
          }
        }
      __syncthreads();
      // thresholds for pass B (reuse mpl)
#pragma unroll
      for (int rf = 0; rf < 2; ++rf)
#pragma unroll
        for (int r = 0; r < 4; ++r) {
          int rowl = wr * 32 + rf * 16 + (l >> 4) * 4 + r;
          mpl[rf][r] = __uint_as_float(mrow[rowl]) + EPS;
        }
    }
  }
  __syncthreads();

  // exact rescreen: 4 threads per row, strided over that row's candidates
  {
    int row = t >> 2;
    int cnt = rcnt[row];
    float b = INFINITY; int bi = N_EMB;
    if (cnt <= CK) {
      const float* zr = zt + (size_t)(n0z + row) * C_DIM;
      float z2v = z2g[n0z + row];
      for (int p2 = (t & 3); p2 < cnt; p2 += 4) {
        int col = rcol[row * CK + p2];
        float s = exact_score(zr, emb + (size_t)col * C_DIM, z2v, e2g[col]);
        if (s < b || (s == b && col < bi)) { b = s; bi = col; }
      }
    }
#pragma unroll
    for (int m = 1; m <= 2; m <<= 1) {
      float ob = __shfl_xor(b, m, 64);
      int oi2 = __shfl_xor(bi, m, 64);
      if (ob < b || (ob == b && oi2 < bi)) { b = ob; bi = oi2; }
    }
    if ((t & 3) == 0 && cnt <= CK) {
      cd[ns * N_Z + n0z + row] = b;
      ci[ns * N_Z + n0z + row] = bi;
    }
  }

  // overflow fallback: exact scan of the full split for any overflowed row
  if (t < MBLK && rcnt[t] > CK) {
    int p = atomicAdd(&novf, 1);
    if (p < 16) ovfr[p] = t;
  }
  __syncthreads();
  int no = min(novf, 16);
  for (int oi = 0; oi < no; ++oi) {
    int row = ovfr[oi];
    const float* zr = zt + (size_t)(n0z + row) * C_DIM;
    float z2v = z2g[n0z + row];
    float b = INFINITY; int bi = N_EMB;
#pragma unroll
    for (int q = 0; q < 2; ++q) {
      int col = ns * SPLITC + t * 2 + q;
      float s = exact_score(zr, emb + (size_t)col * C_DIM, z2v, e2g[col]);
      if (s < b || (s == b && col < bi)) { b = s; bi = col; }
    }
#pragma unroll
    for (int m = 1; m <= 32; m <<= 1) {
      float ob = __shfl_xor(b, m, 64);
      int oi2 = __shfl_xor(bi, m, 64);
      if (ob < b || (ob == b && oi2 < bi)) { b = ob; bi = oi2; }
    }
    if (l == 0) { wbs[w] = b; wis[w] = bi; }
    __syncthreads();
    if (t == 0) {
      for (int w2 = 1; w2 < 8; ++w2)
        if (wbs[w2] < b || (wbs[w2] == b && wis[w2] < bi)) { b = wbs[w2]; bi = wis[w2]; }
      cd[ns * N_Z + n0z + row] = b;
      ci[ns * N_Z + n0z + row] = bi;
    }
    __syncthreads();
  }
}

// merge NSPLIT candidates per row, write indices (as float) and gather z_q
__global__ void vq_out(const float* __restrict__ emb, const float* __restrict__ cd,
                       const int* __restrict__ ci, float* __restrict__ out) {
  __shared__ int sidx[32];
  int t = threadIdx.x;
  int n0 = blockIdx.x * 32;
  if (t < 32) {
    int n = n0 + t;
    float b = INFINITY;
    int bi = 0;
    for (int ns = 0; ns < NSPLIT; ++ns) {        // ascending split = ascending idx
      float d = cd[ns * N_Z + n];
      int i = ci[ns * N_Z + n];
      if (d < b || (d == b && i < bi)) { b = d; bi = i; }
    }
    sidx[t] = bi;
    out[ZQ_ELEMS + n] = (float)bi;
  }
  __syncthreads();
  int bb = n0 >> 10, hw0 = n0 & 1023;
  int nl = t & 31, cg = t >> 5;
#pragma unroll
  for (int p = 0; p < 8; ++p) {
    int c0 = cg * 4 + p * 32;
    float4 v = *(const float4*)(emb + (size_t)sidx[nl] * C_DIM + c0);
    out[((size_t)bb * C_DIM + c0 + 0) * HWB + hw0 + nl] = v.x;
    out[((size_t)bb * C_DIM + c0 + 1) * HWB + hw0 + nl] = v.y;
    out[((size_t)bb * C_DIM + c0 + 2) * HWB + hw0 + nl] = v.z;
    out[((size_t)bb * C_DIM + c0 + 3) * HWB + hw0 + nl] = v.w;
  }
}

extern "C" void kernel_launch(void* const* d_in, const int* in_sizes, int n_in,
                              void* d_out, int out_size, void* d_ws, size_t ws_size,
                              hipStream_t stream) {
  const float* hid = (const float*)d_in[0];
  const float* emb = (const float*)d_in[1];
  float* out = (float*)d_out;

  float* zt = (float*)d_ws;                        // 8 MB
  float* z2 = zt + (size_t)N_Z * C_DIM;            // 8192
  float* e2 = z2 + N_Z;                            // 8192
  float* cd = e2 + N_EMB;                          // 65536
  int* ci = (int*)(cd + (size_t)NSPLIT * N_Z);     // 65536
  u16* zbf = (u16*)(ci + (size_t)NSPLIT * N_Z);    // 4 MB
  u16* ebf = zbf + (size_t)N_Z * C_DIM;            // 4 MB

  vq_tr<<<2048, 256, 0, stream>>>(hid, zt, zbf);
  vq_norms<<<64, 256, 0, stream>>>(zt, emb, z2, e2, ebf);
  vq_filter<<<(N_Z / MBLK) * NSPLIT, 512, 0, stream>>>(zbf, ebf, zt, emb, z2, e2, cd, ci);
  vq_out<<<N_Z / 32, 256, 0, stream>>>(emb, cd, ci, out);
}

// Round 9
// 219.327 us; speedup vs baseline: 3.6908x; 1.0544x over previous
//
#include <hip/hip_runtime.h>
#include <hip/hip_bf16.h>
#include <math.h>

#define C_DIM 256
#define N_EMB 8192
#define N_Z   8192
#define HWB   1024
#define MBLK  128                 // z rows per filter block
#define NSPLIT 4                  // codebook splits (grid 256 = 1 block/CU)
#define SPLITC (N_EMB / NSPLIT)   // 2048 cols per split
#define NT    128                 // e cols per tile
#define NTILES (SPLITC / NT)      // 16
#define NCHUNK (NTILES * 2)       // 32 e-chunks (128 cols x 128 k) per pass
#define CK    32                  // candidate slots per row
#define EPS   1.1e-3f             // >= 2*hard bound on |s_exact - s_approx| (~7.8e-4)
#define ZQ_ELEMS (N_Z * C_DIM)

typedef __attribute__((ext_vector_type(8))) short bf16x8;
typedef __attribute__((ext_vector_type(4))) float f32x4;
typedef unsigned short u16;
typedef unsigned int u32;

__device__ __forceinline__ float sqf(float x) { return __fmul_rn(x, x); }

__device__ __forceinline__ u16 f2bf(float v) {
  __hip_bfloat16 h = __float2bfloat16(v);
  u16 r; __builtin_memcpy(&r, &h, 2); return r;
}

// async global->LDS, 16B per lane; LDS dest = wave-uniform base + lane*16
__device__ __forceinline__ void g2l16(const u16* g, u16* l) {
  __builtin_amdgcn_global_load_lds(
      (const __attribute__((address_space(1))) unsigned int*)(const void*)g,
      (__attribute__((address_space(3))) unsigned int*)(void*)l, 16, 0, 0);
}

// Exact replication of numpy pairwise summation of 256 squared elements.
template <int STRIDE>
__device__ float pw_sumsq_256(const float* __restrict__ a) {
  float h[2];
#pragma unroll
  for (int hh = 0; hh < 2; ++hh) {
    const float* p = a + hh * 128 * STRIDE;
    float r0 = sqf(p[0 * STRIDE]), r1 = sqf(p[1 * STRIDE]);
    float r2 = sqf(p[2 * STRIDE]), r3 = sqf(p[3 * STRIDE]);
    float r4 = sqf(p[4 * STRIDE]), r5 = sqf(p[5 * STRIDE]);
    float r6 = sqf(p[6 * STRIDE]), r7 = sqf(p[7 * STRIDE]);
    for (int i = 8; i < 128; i += 8) {
      r0 = __fadd_rn(r0, sqf(p[(i + 0) * STRIDE]));
      r1 = __fadd_rn(r1, sqf(p[(i + 1) * STRIDE]));
      r2 = __fadd_rn(r2, sqf(p[(i + 2) * STRIDE]));
      r3 = __fadd_rn(r3, sqf(p[(i + 3) * STRIDE]));
      r4 = __fadd_rn(r4, sqf(p[(i + 4) * STRIDE]));
      r5 = __fadd_rn(r5, sqf(p[(i + 5) * STRIDE]));
      r6 = __fadd_rn(r6, sqf(p[(i + 6) * STRIDE]));
      r7 = __fadd_rn(r7, sqf(p[(i + 7) * STRIDE]));
    }
    h[hh] = __fadd_rn(__fadd_rn(__fadd_rn(r0, r1), __fadd_rn(r2, r3)),
                      __fadd_rn(__fadd_rn(r4, r5), __fadd_rn(r6, r7)));
  }
  return __fadd_rn(h[0], h[1]);
}

// exact sequential dot (k = 0..255 ascending, xyzw) -- identical op order to
// the verified exact path of rounds 1-8.
__device__ __forceinline__ float exact_score(const float* __restrict__ zr,
                                             const float* __restrict__ er,
                                             float z2v, float e2v) {
  float d = 0.f;
  for (int k4 = 0; k4 < 64; ++k4) {
    float4 a4 = *(const float4*)(zr + k4 * 4);
    float4 b4 = *(const float4*)(er + k4 * 4);
    d = fmaf(a4.x, b4.x, d); d = fmaf(a4.y, b4.y, d);
    d = fmaf(a4.z, b4.z, d); d = fmaf(a4.w, b4.w, d);
  }
  return __fsub_rn(__fadd_rn(z2v, e2v), __fmul_rn(2.f, d));
}

// Transpose hid [b][c][hw] -> zt fp32 [n][c] and zbf bf16 [n][c].
__global__ void vq_tr(const float* __restrict__ hid, float* __restrict__ zt,
                      u16* __restrict__ zbf) {
  __shared__ float tl[32][33];
  int t = threadIdx.x;
  int tx = t & 31, ty = t >> 5;
  int bb = blockIdx.x >> 8;
  int r = blockIdx.x & 255;
  int cT = r >> 5, hwT = r & 31;
#pragma unroll
  for (int p = 0; p < 4; ++p)
    tl[ty + p * 8][tx] =
        hid[((size_t)bb * C_DIM + cT * 32 + ty + p * 8) * HWB + hwT * 32 + tx];
  __syncthreads();
#pragma unroll
  for (int p = 0; p < 4; ++p) {
    float v = tl[tx][ty + p * 8];
    size_t oi = ((size_t)bb * HWB + hwT * 32 + ty + p * 8) * C_DIM + cT * 32 + tx;
    zt[oi] = v;
    zbf[oi] = f2bf(v);
  }
}

// blocks 0..31: e2 + ebf; blocks 32..63: z2 (from zt)
__global__ void vq_norms(const float* __restrict__ zt, const float* __restrict__ emb,
                         float* __restrict__ z2, float* __restrict__ e2,
                         u16* __restrict__ ebf) {
  int t = threadIdx.x, b = blockIdx.x;
  if (b < 32) {
    int r = b * 256 + t;
    e2[r] = pw_sumsq_256<1>(emb + (size_t)r * C_DIM);
    for (int k4 = 0; k4 < 64; ++k4) {
      float4 v = *(const float4*)(emb + (size_t)r * C_DIM + k4 * 4);
      ushort4 o;
      o.x = f2bf(v.x); o.y = f2bf(v.y); o.z = f2bf(v.z); o.w = f2bf(v.w);
      *(ushort4*)(ebf + (size_t)r * C_DIM + k4 * 4) = o;
    }
  } else {
    int n = (b - 32) * 256 + t;
    z2[n] = pw_sumsq_256<1>(zt + (size_t)n * C_DIM);
  }
}

// Two-pass MFMA filter + exact rescreen.
// z (A-operand) lives in REGISTERS: 16 bf16x8 frags per wave (64 VGPR), loaded
// once from zbf with the same lane->k mapping as the B LDS reads (consistent
// shared k-permutation cancels in the dot). e is staged by global_load_lds
// (width 16) into a double-buffered 2x32KB tile; one barrier per step drains
// DMA + LDS reads (m97 2-phase). 1 block/CU (grid 256), 8 waves 4x2, wave
// tile 32x64, acc[2][4] (32 VGPR). Pass A: per-lane running min -> one
// reduce + LDS atomicMin. Pass B: recompute (bit-identical) + tight-threshold
// appends. Candidates re-scored EXACTLY; overflow -> exact full-split scan.
__global__ __launch_bounds__(512, 2) void vq_filter(
    const u16* __restrict__ zbf, const u16* __restrict__ ebf,
    const float* __restrict__ zt, const float* __restrict__ emb,
    const float* __restrict__ z2g, const float* __restrict__ e2g,
    float* __restrict__ cd, int* __restrict__ ci) {
  __shared__ u16 el[2][16384];        // 64 KB: per buf, 2 sub-tiles of 128r x 64k
  __shared__ float e2l[SPLITC];       // 8 KB
  __shared__ u32 mrow[MBLK];          // float bits of row min
  __shared__ u16 rcol[MBLK * CK];     // 8 KB
  __shared__ int rcnt[MBLK];
  __shared__ int ovfr[16];
  __shared__ int novf;
  __shared__ float wbs[8];
  __shared__ int wis[8];

  int t = threadIdx.x;
  int mb = blockIdx.x >> 2;           // 0..63
  int ns = blockIdx.x & 3;            // XCD x sees only ns = x&3 -> L2-local split
  int n0z = mb * MBLK;
  int l = t & 63;
  int w = t >> 6;
  int wr = w >> 1, wc = w & 1;        // 4 x 2 wave grid, wave tile 32 x 64

  if (t < MBLK) { rcnt[t] = 0; mrow[t] = 0x7f800000u; }
  if (t == 0) novf = 0;
  for (int i = t; i < SPLITC; i += 512) e2l[i] = e2g[ns * SPLITC + i];

  // A fragments in registers: A[rf][f] covers rows wr*32+rf*16+(l&15),
  // k in [f*32 + (l>>4)*8, +8)  -- 64 VGPR, reused by both passes.
  bf16x8 A[2][8];
#pragma unroll
  for (int rf = 0; rf < 2; ++rf)
#pragma unroll
    for (int f = 0; f < 8; ++f)
      A[rf][f] = *(const bf16x8*)(zbf +
          (size_t)(n0z + wr * 32 + rf * 16 + (l & 15)) * C_DIM + f * 32 + ((l >> 4) << 3));

  float z2r[2][4];
#pragma unroll
  for (int rf = 0; rf < 2; ++rf)
#pragma unroll
    for (int r = 0; r < 4; ++r)
      z2r[rf][r] = z2g[n0z + wr * 32 + rf * 16 + (l >> 4) * 4 + r];

  float mpl[2][4];
#pragma unroll
  for (int rf = 0; rf < 2; ++rf)
#pragma unroll
    for (int r = 0; r < 4; ++r) mpl[rf][r] = INFINITY;

  const f32x4 vzero = {0.f, 0.f, 0.f, 0.f};
  const u16* esplit = ebf + (size_t)(ns * SPLITC) * C_DIM;

  // stage chunk c (tile c>>1, k-half c&1) into buffer nb: 4 DMA ops per wave
#define STAGE_E(nb_, c_)                                                      \
  {                                                                           \
    int tn_ = (c_) >> 1, kcn_ = ((c_) & 1) << 7;                              \
    const u16* bs_ = esplit + (size_t)(tn_ * NT) * C_DIM + kcn_;              \
    _Pragma("unroll")                                                         \
    for (int p_ = 0; p_ < 4; ++p_) {                                          \
      int o_ = (w * 4 + p_) * 64 + l;                                         \
      int g2_ = o_ >> 10, rr_ = (o_ >> 3) & 127, p3_ = o_ & 7;                \
      g2l16(bs_ + (size_t)rr_ * C_DIM + g2_ * 64 + ((p3_ ^ (rr_ & 7)) << 3),  \
            &el[nb_][(w * 4 + p_) * 512]);                                    \
    }                                                                         \
  }

  // prologue: chunk 0 -> buf 0; barrier drains DMA (vmcnt 0) + e2l/rcnt init
  STAGE_E(0, 0)
  __syncthreads();

  int cur = 0;
#pragma unroll 1
  for (int pass = 0; pass < 2; ++pass) {
#pragma unroll 1
    for (int tile = 0; tile < NTILES; ++tile) {
      f32x4 acc[2][4];
#pragma unroll
      for (int rf = 0; rf < 2; ++rf)
#pragma unroll
        for (int cf = 0; cf < 4; ++cf) acc[rf][cf] = vzero;

#pragma unroll
      for (int half = 0; half < 2; ++half) {
        int c = tile * 2 + half;
        if (!(pass == 1 && c == NCHUNK - 1)) STAGE_E(cur ^ 1, (c + 1) & (NCHUNK - 1))
#pragma unroll
        for (int kf = 0; kf < 4; ++kf) {
          int g2 = kf >> 1, ks = kf & 1;
          int phys = (((ks * 4 + (l >> 4)) ^ (l & 7)) << 3);
#pragma unroll
          for (int cf = 0; cf < 4; ++cf) {
            bf16x8 bfr = *(const bf16x8*)(&el[cur][g2 * 8192 +
                           (wc * 64 + cf * 16 + (l & 15)) * 64 + phys]);
            acc[0][cf] = __builtin_amdgcn_mfma_f32_16x16x32_bf16(A[0][half * 4 + kf], bfr, acc[0][cf], 0, 0, 0);
            acc[1][cf] = __builtin_amdgcn_mfma_f32_16x16x32_bf16(A[1][half * 4 + kf], bfr, acc[1][cf], 0, 0, 0);
          }
        }
        __syncthreads();   // drains next-chunk DMA + this buffer's reads
        cur ^= 1;
      }
      // per-tile epilogue (registers + resident LDS only)
      float e2s[4];
#pragma unroll
      for (int cf = 0; cf < 4; ++cf)
        e2s[cf] = e2l[tile * NT + wc * 64 + cf * 16 + (l & 15)];
      if (pass == 0) {
#pragma unroll
        for (int rf = 0; rf < 2; ++rf)
#pragma unroll
          for (int r = 0; r < 4; ++r) {
            float z2v = z2r[rf][r];
            float mn = mpl[rf][r];
#pragma unroll
            for (int cf = 0; cf < 4; ++cf)
              mn = fminf(mn, fmaf(-2.f, acc[rf][cf][r], z2v + e2s[cf]));
            mpl[rf][r] = mn;
          }
      } else {
        int ne0 = ns * SPLITC + tile * NT;
#pragma unroll
        for (int rf = 0; rf < 2; ++rf)
#pragma unroll
          for (int r = 0; r < 4; ++r) {
            int rowl = wr * 32 + rf * 16 + (l >> 4) * 4 + r;
            float z2v = z2r[rf][r];
            float thr = mpl[rf][r];
#pragma unroll
            for (int cf = 0; cf < 4; ++cf) {
              float s = fmaf(-2.f, acc[rf][cf][r], z2v + e2s[cf]);
              if (s <= thr) {
                int pos = atomicAdd(&rcnt[rowl], 1);
                if (pos < CK)
                  rcol[rowl * CK + pos] = (u16)(ne0 + wc * 64 + cf * 16 + (l & 15));
              }
            }
          }
      }
    }
    if (pass == 0) {
      // one cross-lane reduce + atomicMin (float bits; all s > 0)
#pragma unroll
      for (int rf = 0; rf < 2; ++rf)
#pragma unroll
        for (int r = 0; r < 4; ++r) {
          float mn = mpl[rf][r];
#pragma unroll
          for (int m = 1; m < 16; m <<= 1)
            mn = fminf(mn, __shfl_xor(mn, m, 64));
          if ((l & 15) == 0) {
            int rowl = wr * 32 + rf * 16 + (l >> 4) * 4 + r;
            atomicMin(&mrow[rowl], __float_as_uint(mn));
          }
        }
      __syncthreads();
#pragma unroll
      for (int rf = 0; rf < 2; ++rf)
#pragma unroll
        for (int r = 0; r < 4; ++r) {
          int rowl = wr * 32 + rf * 16 + (l >> 4) * 4 + r;
          mpl[rf][r] = __uint_as_float(mrow[rowl]) + EPS;
        }
    }
  }
  __syncthreads();

  // exact rescreen: 4 threads per row, strided over that row's candidates
  {
    int row = t >> 2;
    int cnt = rcnt[row];
    float b = INFINITY; int bi = N_EMB;
    if (cnt <= CK) {
      const float* zr = zt + (size_t)(n0z + row) * C_DIM;
      float z2v = z2g[n0z + row];
      for (int p2 = (t & 3); p2 < cnt; p2 += 4) {
        int col = rcol[row * CK + p2];
        float s = exact_score(zr, emb + (size_t)col * C_DIM, z2v, e2g[col]);
        if (s < b || (s == b && col < bi)) { b = s; bi = col; }
      }
    }
#pragma unroll
    for (int m = 1; m <= 2; m <<= 1) {
      float ob = __shfl_xor(b, m, 64);
      int oi2 = __shfl_xor(bi, m, 64);
      if (ob < b || (ob == b && oi2 < bi)) { b = ob; bi = oi2; }
    }
    if ((t & 3) == 0 && cnt <= CK) {
      cd[ns * N_Z + n0z + row] = b;
      ci[ns * N_Z + n0z + row] = bi;
    }
  }

  // overflow fallback: exact scan of the full split for any overflowed row
  if (t < MBLK && rcnt[t] > CK) {
    int p = atomicAdd(&novf, 1);
    if (p < 16) ovfr[p] = t;
  }
  __syncthreads();
  int no = min(novf, 16);
  for (int oi = 0; oi < no; ++oi) {
    int row = ovfr[oi];
    const float* zr = zt + (size_t)(n0z + row) * C_DIM;
    float z2v = z2g[n0z + row];
    float b = INFINITY; int bi = N_EMB;
#pragma unroll
    for (int q = 0; q < 4; ++q) {
      int col = ns * SPLITC + t * 4 + q;
      float s = exact_score(zr, emb + (size_t)col * C_DIM, z2v, e2g[col]);
      if (s < b || (s == b && col < bi)) { b = s; bi = col; }
    }
#pragma unroll
    for (int m = 1; m <= 32; m <<= 1) {
      float ob = __shfl_xor(b, m, 64);
      int oi2 = __shfl_xor(bi, m, 64);
      if (ob < b || (ob == b && oi2 < bi)) { b = ob; bi = oi2; }
    }
    if (l == 0) { wbs[w] = b; wis[w] = bi; }
    __syncthreads();
    if (t == 0) {
      for (int w2 = 1; w2 < 8; ++w2)
        if (wbs[w2] < b || (wbs[w2] == b && wis[w2] < bi)) { b = wbs[w2]; bi = wis[w2]; }
      cd[ns * N_Z + n0z + row] = b;
      ci[ns * N_Z + n0z + row] = bi;
    }
    __syncthreads();
  }
}

// merge NSPLIT candidates per row, write indices (as float) and gather z_q
__global__ void vq_out(const float* __restrict__ emb, const float* __restrict__ cd,
                       const int* __restrict__ ci, float* __restrict__ out) {
  __shared__ int sidx[32];
  int t = threadIdx.x;
  int n0 = blockIdx.x * 32;
  if (t < 32) {
    int n = n0 + t;
    float b = INFINITY;
    int bi = 0;
    for (int ns = 0; ns < NSPLIT; ++ns) {        // ascending split = ascending idx
      float d = cd[ns * N_Z + n];
      int i = ci[ns * N_Z + n];
      if (d < b || (d == b && i < bi)) { b = d; bi = i; }
    }
    sidx[t] = bi;
    out[ZQ_ELEMS + n] = (float)bi;
  }
  __syncthreads();
  int bb = n0 >> 10, hw0 = n0 & 1023;
  int nl = t & 31, cg = t >> 5;
#pragma unroll
  for (int p = 0; p < 8; ++p) {
    int c0 = cg * 4 + p * 32;
    float4 v = *(const float4*)(emb + (size_t)sidx[nl] * C_DIM + c0);
    out[((size_t)bb * C_DIM + c0 + 0) * HWB + hw0 + nl] = v.x;
    out[((size_t)bb * C_DIM + c0 + 1) * HWB + hw0 + nl] = v.y;
    out[((size_t)bb * C_DIM + c0 + 2) * HWB + hw0 + nl] = v.z;
    out[((size_t)bb * C_DIM + c0 + 3) * HWB + hw0 + nl] = v.w;
  }
}

extern "C" void kernel_launch(void* const* d_in, const int* in_sizes, int n_in,
                              void* d_out, int out_size, void* d_ws, size_t ws_size,
                              hipStream_t stream) {
  const float* hid = (const float*)d_in[0];
  const float* emb = (const float*)d_in[1];
  float* out = (float*)d_out;

  float* zt = (float*)d_ws;                        // 8 MB
  float* z2 = zt + (size_t)N_Z * C_DIM;            // 8192
  float* e2 = z2 + N_Z;                            // 8192
  float* cd = e2 + N_EMB;                          // NSPLIT*8192
  int* ci = (int*)(cd + (size_t)NSPLIT * N_Z);     // NSPLIT*8192
  u16* zbf = (u16*)(ci + (size_t)NSPLIT * N_Z);    // 4 MB
  u16* ebf = zbf + (size_t)N_Z * C_DIM;            // 4 MB

  vq_tr<<<2048, 256, 0, stream>>>(hid, zt, zbf);
  vq_norms<<<64, 256, 0, stream>>>(zt, emb, z2, e2, ebf);
  vq_filter<<<(N_Z / MBLK) * NSPLIT, 512, 0, stream>>>(zbf, ebf, zt, emb, z2, e2, cd, ci);
  vq_out<<<N_Z / 32, 256, 0, stream>>>(emb, cd, ci, out);
}